// Round 7
// baseline (280.170 us; speedup 1.0000x reference)
//
#include <hip/hip_runtime.h>

// SelfAttention (B=4, C=256, H=W=64): fused projections + flash attention.
// Round 7: hybrid flash = r3 cooperative S-through-LDS (non-redundant, cheap
// softmax: 8 exps/thread) + r6 innovations (direct-global K/Q/V fragment
// loads, no-max exp2 softmax, register epilogue) + double-buffered S tile
// (2 barriers/iter instead of 4). r6 post-mortem: register-resident softmax
// multiplied exp+pack VALU by the x4 S-redundancy -> 56us of VALU. Here
// softmax VALU is spread over 512 threads once.
// k_proj: W fragments now loaded direct from global (tiny L2-resident matrix),
// halving staging stores + LDS.

#define B_ 4
#define C_ 256
#define N_ 4096
#define CQK 32

typedef __attribute__((ext_vector_type(8))) short short8;
typedef __attribute__((ext_vector_type(4))) short short4v;
typedef __attribute__((ext_vector_type(16))) float f32x16;
typedef __attribute__((ext_vector_type(4))) float f32x4;

__device__ __forceinline__ unsigned short f2bf(float f) {
  unsigned int u = __builtin_bit_cast(unsigned int, f);
  u = (u + 0x7fffu + ((u >> 16) & 1u)) >> 16;  // RNE
  return (unsigned short)u;
}
__device__ __forceinline__ float bf2f(unsigned short s) {
  unsigned int u = ((unsigned int)s) << 16;
  return __builtin_bit_cast(float, u);
}
__device__ __forceinline__ f32x16 mfma16(short8 a, short8 b, f32x16 c) {
  return __builtin_amdgcn_mfma_f32_32x32x16_bf16(a, b, c, 0, 0, 0);
}
// swizzled element index into bf16 LDS tiles (16B granules XORed by row)
__device__ __forceinline__ int swz64(int row, int col) {
  return row * 64 + ((((col >> 3) ^ row) & 7) << 3) + (col & 7);
}

// ---------------- kernel 1: prep (x transpose+split, weight splits) ----------
__global__ __launch_bounds__(256) void k_prep(
    const float* __restrict__ x, unsigned short* __restrict__ xthi,
    unsigned short* __restrict__ xtlo,
    const float* __restrict__ Wq, const float* __restrict__ Wk,
    const float* __restrict__ Wv,
    unsigned short* __restrict__ wqh, unsigned short* __restrict__ wql,
    unsigned short* __restrict__ wkh, unsigned short* __restrict__ wkl,
    unsigned short* __restrict__ wvh, unsigned short* __restrict__ wvl) {
  __shared__ __align__(16) float tile[64 * 65];
  const int bi = blockIdx.x;
  const int t = threadIdx.x;
  if (bi < 1024) {
    const int it = bi & 63, ct = (bi >> 6) & 3, b = bi >> 8;
    const int i0 = it * 64, c0 = ct * 64;
    {
      const int i = t & 63, cb = t >> 6;
#pragma unroll
      for (int z = 0; z < 16; ++z) {
        const int c = z * 4 + cb;
        tile[i * 65 + c] = x[(b * C_ + c0 + c) * N_ + i0 + i];
      }
    }
    __syncthreads();
    {
      const int ii = t >> 2, p = t & 3;
      short8 h0, h1, l0, l1;
#pragma unroll
      for (int e = 0; e < 16; ++e) {
        const float f = tile[ii * 65 + p * 16 + e];
        const unsigned short hb = f2bf(f);
        const unsigned short lb = f2bf(f - bf2f(hb));
        if (e < 8) { h0[e] = (short)hb; l0[e] = (short)lb; }
        else       { h1[e - 8] = (short)hb; l1[e - 8] = (short)lb; }
      }
      const int base = (b * N_ + i0 + ii) * C_ + c0 + p * 16;
      *(short8*)(xthi + base) = h0;
      *(short8*)(xthi + base + 8) = h1;
      *(short8*)(xtlo + base) = l0;
      *(short8*)(xtlo + base + 8) = l1;
    }
  } else {
    const int e = (bi - 1024) * 256 + t;  // < 81920
    const float* src; unsigned short *hi, *lo; int idx;
    if (e < 8192)        { src = Wq; hi = wqh; lo = wql; idx = e; }
    else if (e < 16384)  { src = Wk; hi = wkh; lo = wkl; idx = e - 8192; }
    else                 { src = Wv; hi = wvh; lo = wvl; idx = e - 16384; }
    const float f = src[idx];
    const unsigned short h = f2bf(f);
    hi[idx] = h;
    lo[idx] = f2bf(f - bf2f(h));
  }
}

// ---------------- kernel 2: fused q/k/v projection GEMM ----------------
// q rows scaled by log2(e) so flash can use raw exp2 (no max subtraction).
// W fragments direct from global (L2-resident 320x256 matrix, reused by all
// 64 i-tiles x 4 batches); only x^T staged in LDS.
__global__ __launch_bounds__(256) void k_proj(
    const unsigned short* __restrict__ wqh, const unsigned short* __restrict__ wql,
    const unsigned short* __restrict__ wkh, const unsigned short* __restrict__ wkl,
    const unsigned short* __restrict__ wvh, const unsigned short* __restrict__ wvl,
    const unsigned short* __restrict__ xthi, const unsigned short* __restrict__ xtlo,
    const float* __restrict__ bq, const float* __restrict__ bk,
    const float* __restrict__ bv,
    unsigned short* __restrict__ qhg, unsigned short* __restrict__ qlg,
    unsigned short* __restrict__ khg, unsigned short* __restrict__ klg,
    unsigned short* __restrict__ vg) {
  __shared__ __align__(16) char sm[16640];
  unsigned short* bxh = (unsigned short*)sm;       // [64][64] x^T hi (swizzled)
  unsigned short* bxl = bxh + 4096;
  float* qt = (float*)sm;                          // epilogue reuse: [64][65] f32

  const int it = blockIdx.x, ot = blockIdx.y, b = blockIdx.z;
  const int i0 = it * 64, o0 = ot * 64;
  const int t = threadIdx.x, lane = t & 63, w = t >> 6, h = lane >> 5;
  const int mb = w >> 1, nb = w & 1;
  const int srow = t >> 2, sp = t & 3;
  const int l31 = lane & 31;

  // per-lane W row pointers (wave-uniform base + l31*C)
  const unsigned short *wmh, *wml;
  if (ot == 0) {
    if (mb == 0) { wmh = wqh + l31 * C_; wml = wql + l31 * C_; }
    else         { wmh = wkh + l31 * C_; wml = wkl + l31 * C_; }
  } else {
    const int vr = o0 - 64 + 32 * mb + l31;
    wmh = wvh + vr * C_; wml = wvl + vr * C_;
  }
  const unsigned short* xh = xthi + (b * N_ + i0 + srow) * C_;
  const unsigned short* xl = xtlo + (b * N_ + i0 + srow) * C_;

  f32x16 acc;
#pragma unroll
  for (int e = 0; e < 16; ++e) acc[e] = 0.f;
  const int m = 32 * mb + l31;
  const int n = 32 * nb + l31;

  for (int kt = 0; kt < 4; ++kt) {
    const int cb = kt * 64 + sp * 16;
    *(short8*)&bxh[swz64(srow, sp * 16)]     = *(const short8*)(xh + cb);
    *(short8*)&bxh[swz64(srow, sp * 16 + 8)] = *(const short8*)(xh + cb + 8);
    *(short8*)&bxl[swz64(srow, sp * 16)]     = *(const short8*)(xl + cb);
    *(short8*)&bxl[swz64(srow, sp * 16 + 8)] = *(const short8*)(xl + cb + 8);
    __syncthreads();
#pragma unroll
    for (int kk = 0; kk < 4; ++kk) {
      const int kb = kt * 64 + kk * 16 + h * 8;
      const short8 ah  = *(const short8*)(wmh + kb);
      const short8 al2 = *(const short8*)(wml + kb);
      const int kbl = kk * 16 + h * 8;
      const short8 bh  = *(const short8*)&bxh[swz64(n, kbl)];
      const short8 bl2 = *(const short8*)&bxl[swz64(n, kbl)];
      acc = mfma16(ah, bh, acc);
      acc = mfma16(ah, bl2, acc);
      acc = mfma16(al2, bh, acc);
    }
    __syncthreads();
  }

  if (ot > 0) {  // v epilogue: direct [B][C][N] bf16 store
#pragma unroll
    for (int e = 0; e < 16; ++e) {
      const int r = 32 * mb + (e & 3) + 8 * (e >> 2) + 4 * h;
      const int oc = o0 - 64 + r;
      vg[(b * C_ + oc) * N_ + i0 + n] = f2bf(acc[e] + bv[oc]);
    }
  } else {  // q/k epilogue: LDS transpose -> [B][N][32] hi/lo
#pragma unroll
    for (int e = 0; e < 16; ++e) {
      const int r = 32 * mb + (e & 3) + 8 * (e >> 2) + 4 * h;
      const float bias = (r < 32) ? bq[r] : bk[r - 32];
      float val = acc[e] + bias;
      if (r < 32) val *= 1.4426950408889634f;  // log2(e): flash uses raw exp2
      qt[r * 65 + n] = val;
    }
    __syncthreads();
    const int ii = t >> 2;
    short8 hv0, hv1, lv0, lv1;
#pragma unroll
    for (int e = 0; e < 16; ++e) {
      const float f = qt[(sp * 16 + e) * 65 + ii];
      const unsigned short hb = f2bf(f);
      const unsigned short lb = f2bf(f - bf2f(hb));
      if (e < 8) { hv0[e] = (short)hb; lv0[e] = (short)lb; }
      else       { hv1[e - 8] = (short)hb; lv1[e - 8] = (short)lb; }
    }
    if (sp < 2) {
      const int base = (b * N_ + i0 + ii) * CQK + sp * 16;
      *(short8*)(qhg + base) = hv0; *(short8*)(qhg + base + 8) = hv1;
      *(short8*)(qlg + base) = lv0; *(short8*)(qlg + base + 8) = lv1;
    } else {
      const int base = (b * N_ + i0 + ii) * CQK + sp * 16 - 32;
      *(short8*)(khg + base) = hv0; *(short8*)(khg + base + 8) = hv1;
      *(short8*)(klg + base) = lv0; *(short8*)(klg + base + 8) = lv1;
    }
  }
}

// ---------------- kernel 3: flash attention (dbuf S, 2 barriers/iter) -------
// 512 blocks x 512 thr, blk=(qt<<3)|(b<<1)|half, 32 iters of Ktile=64.
// Waves 0-3 compute S quadrants (direct-global Q/K frags) -> swizzled f32 in
// stf[kt&1]; all 512 threads softmax (8 exp2 each, no max: q pre-scaled by
// log2e) writing bf16 P in place; all 8 waves PV (wave w = channels
// 32w..32w+32, V frags direct from global). Register epilogue: O/l as f16
// [c][i] + l stats; no big LDS transpose.
__global__ __launch_bounds__(512, 4) void k_flash(
    const unsigned short* __restrict__ qhg, const unsigned short* __restrict__ qlg,
    const unsigned short* __restrict__ khg, const unsigned short* __restrict__ klg,
    const unsigned short* __restrict__ vg,
    unsigned short* __restrict__ Opart, float* __restrict__ mlpart) {
  __shared__ __align__(16) float stf[2][64 * 64];  // 32 KB dbuf S/P
  __shared__ __align__(16) float lsc[64];          // 1/l broadcast (epilogue)

  // XCD-aware: blk%8 -> fixed (b,half) per XCD; per-XCD K/V ~1.3MB < L2.
  const int blk = blockIdx.x;
  const int b = (blk >> 1) & 3;
  const int half = blk & 1;
  const int qt_ = blk >> 3;
  const int q0 = qt_ * 64;
  const int jbase = half * 2048;
  const int t = threadIdx.x, lane = t & 63, w = t >> 6;
  const int h = lane >> 5, l31 = lane & 31;
  const int r_sm = t >> 3, p_sm = t & 7;
  const int mbs = (w >> 1) & 1, nbs = w & 1;

  // V fragment base: channel crow = 32w+l31 (each 16B read exactly once/block)
  const int crow = 32 * w + l31;
  const unsigned short* vbase = vg + (size_t)(b * C_ + crow) * N_ + h * 8;
  // S-wave fragment bases (waves 0..3)
  const unsigned short* qb_h = qhg + (b * N_ + q0 + 32 * mbs + l31) * CQK + h * 8;
  const unsigned short* qb_l = qlg + (b * N_ + q0 + 32 * mbs + l31) * CQK + h * 8;
  const unsigned short* kb_h = khg + (b * N_ + jbase + 32 * nbs + l31) * CQK + h * 8;
  const unsigned short* kb_l = klg + (b * N_ + jbase + 32 * nbs + l31) * CQK + h * 8;

  f32x16 acc0, acc1;
#pragma unroll
  for (int e = 0; e < 16; ++e) { acc0[e] = 0.f; acc1[e] = 0.f; }
  float l_run = 0.f;

  for (int kt = 0; kt < 32; ++kt) {
    const int j0 = jbase + kt * 64;
    float* sbuf = stf[kt & 1];
    // V frags issued now, consumed after 2 barriers -> natural prefetch
    short8 vf[4];
#pragma unroll
    for (int kk = 0; kk < 4; ++kk)
      vf[kk] = *(const short8*)(vbase + j0 + kk * 16);
    if (w < 4) {
      const short8 qh0 = *(const short8*)(qb_h);
      const short8 qh1 = *(const short8*)(qb_h + 16);
      const short8 ql0 = *(const short8*)(qb_l);
      const short8 ql1 = *(const short8*)(qb_l + 16);
      const unsigned short* kh_p = kb_h + kt * 64 * CQK;
      const unsigned short* kl_p = kb_l + kt * 64 * CQK;
      const short8 kh0 = *(const short8*)(kh_p);
      const short8 kh1 = *(const short8*)(kh_p + 16);
      const short8 kl0 = *(const short8*)(kl_p);
      const short8 kl1 = *(const short8*)(kl_p + 16);
      f32x16 sa;
#pragma unroll
      for (int e = 0; e < 16; ++e) sa[e] = 0.f;
      sa = mfma16(qh0, kh0, sa);   // 3-term hi/lo, kk=0
      sa = mfma16(qh0, kl0, sa);
      sa = mfma16(ql0, kh0, sa);
      sa = mfma16(qh1, kh1, sa);   // kk=1
      sa = mfma16(qh1, kl1, sa);
      sa = mfma16(ql1, kh1, sa);
      const int jn = 32 * nbs + l31;
#pragma unroll
      for (int e = 0; e < 16; ++e) {
        const int ri = 32 * mbs + (e & 3) + 8 * (e >> 2) + 4 * h;
        sbuf[ri * 64 + ((((jn >> 2) ^ ri) & 15) << 2) + (jn & 3)] = sa[e];
      }
    }
    __syncthreads();
    // softmax: thread (r_sm,p_sm) owns cols [8p,8p+8) of row r_sm
    {
      float* p0 = sbuf + r_sm * 64 + ((((2 * p_sm) ^ r_sm) & 15) << 2);
      float* p1 = sbuf + r_sm * 64 + ((((2 * p_sm + 1) ^ r_sm) & 15) << 2);
      const f32x4 a0 = *(const f32x4*)p0;
      const f32x4 a1 = *(const f32x4*)p1;
      float ts = 0.f;
      short8 pv8;
#pragma unroll
      for (int e = 0; e < 4; ++e) {
        const float p = __builtin_amdgcn_exp2f(a0[e]);
        ts += p; pv8[e] = (short)f2bf(p);
      }
#pragma unroll
      for (int e = 0; e < 4; ++e) {
        const float p = __builtin_amdgcn_exp2f(a1[e]);
        ts += p; pv8[4 + e] = (short)f2bf(p);
      }
      ts += __shfl_xor(ts, 1);
      ts += __shfl_xor(ts, 2);
      ts += __shfl_xor(ts, 4);
      l_run += ts;
      *(short8*)p0 = pv8;  // bf16 P overwrites the granule this thread read
    }
    __syncthreads();
    // PV: P A-frags from LDS, V from registers
    {
      const char* stb = (const char*)sbuf;
#pragma unroll
      for (int kk = 0; kk < 4; ++kk) {
        const int g0 = ((4 * kk + 2 * h) ^ l31) & 15;
        const short8 pa0 = *(const short8*)(stb + l31 * 256 + (g0 << 4));
        const short8 pa1 = *(const short8*)(stb + (32 + l31) * 256 + (g0 << 4));
        acc0 = mfma16(pa0, vf[kk], acc0);
        acc1 = mfma16(pa1, vf[kk], acc1);
      }
    }
    // next iter writes stf[kt&1 ^ 1] -> no third barrier needed
  }

  // epilogue: l stats + normalized f16 partials straight from registers
  if (p_sm == 0) {
    lsc[r_sm] = 1.0f / l_run;
    mlpart[blk * 64 + r_sm] = l_run;
  }
  __syncthreads();
  unsigned short* ob = Opart + (size_t)blk * 16384 + crow * 64;
#pragma unroll
  for (int g = 0; g < 4; ++g) {
    const int i0 = 8 * g + 4 * h;
    const f32x4 il0 = *(const f32x4*)&lsc[i0];
    const f32x4 il1 = *(const f32x4*)&lsc[32 + i0];
    short4v hv0, hv1;
#pragma unroll
    for (int d = 0; d < 4; ++d) {
      const _Float16 f0 = (_Float16)(acc0[4 * g + d] * il0[d]);
      const _Float16 f1 = (_Float16)(acc1[4 * g + d] * il1[d]);
      hv0[d] = __builtin_bit_cast(short, f0);
      hv1[d] = __builtin_bit_cast(short, f1);
    }
    *(short4v*)(ob + i0) = hv0;
    *(short4v*)(ob + 32 + i0) = hv1;
  }
}

// ---------------- kernel 4: combine halves + residual ----------------
// Opart holds normalized O per half; merge weights l1,l2 (exp2 domain).
// out = gamma*(l1*O1 + l2*O2)/(l1+l2) + x.
__global__ __launch_bounds__(256) void k_combine(
    const unsigned short* __restrict__ Opart, const float* __restrict__ mlpart,
    const float* __restrict__ x, const float* __restrict__ gamma,
    float* __restrict__ out) {
  const int cb = blockIdx.x;
  const int b = cb & 3, qt_ = cb >> 2;
  const int q0 = qt_ * 64;
  const int blk1 = (qt_ << 3) | (b << 1);
  const int blk2 = blk1 | 1;
  const int t = threadIdx.x;
  const int i = t & 63, cg = t >> 6;

  const float l1 = mlpart[blk1 * 64 + i];
  const float l2 = mlpart[blk2 * 64 + i];
  const float inv = 1.f / (l1 + l2);
  const float gm = gamma[0];
  const float s1 = gm * l1 * inv, s2 = gm * l2 * inv;

  const unsigned short* p1 = Opart + (size_t)blk1 * 16384 + i;
  const unsigned short* p2 = Opart + (size_t)blk2 * 16384 + i;
#pragma unroll 4
  for (int c = cg; c < C_; c += 4) {
    const float o1 = (float)__builtin_bit_cast(_Float16, p1[c * 64]);
    const float o2 = (float)__builtin_bit_cast(_Float16, p2[c * 64]);
    const int g = (b * C_ + c) * N_ + q0 + i;
    out[g] = s1 * o1 + s2 * o2 + x[g];
  }
}

// ---------------- launch ----------------
extern "C" void kernel_launch(void* const* d_in, const int* in_sizes, int n_in,
                              void* d_out, int out_size, void* d_ws, size_t ws_size,
                              hipStream_t stream) {
  const float* x     = (const float*)d_in[0];
  const float* Wq    = (const float*)d_in[1];
  const float* bq    = (const float*)d_in[2];
  const float* Wk    = (const float*)d_in[3];
  const float* bk    = (const float*)d_in[4];
  const float* Wv    = (const float*)d_in[5];
  const float* bv    = (const float*)d_in[6];
  const float* gamma = (const float*)d_in[7];
  float* out = (float*)d_out;
  (void)in_sizes; (void)n_in; (void)out_size; (void)ws_size;

  char* ws = (char*)d_ws;
  size_t off = 0;
  auto carve = [&](size_t bytes) -> char* {
    char* p = ws + off;
    off += (bytes + 255) & ~(size_t)255;
    return p;
  };
  unsigned short* xthi = (unsigned short*)carve((size_t)B_ * N_ * C_ * 2);
  unsigned short* xtlo = (unsigned short*)carve((size_t)B_ * N_ * C_ * 2);
  unsigned short* wqh  = (unsigned short*)carve(32 * 256 * 2);
  unsigned short* wql  = (unsigned short*)carve(32 * 256 * 2);
  unsigned short* wkh  = (unsigned short*)carve(32 * 256 * 2);
  unsigned short* wkl  = (unsigned short*)carve(32 * 256 * 2);
  unsigned short* wvh  = (unsigned short*)carve(256 * 256 * 2);
  unsigned short* wvl  = (unsigned short*)carve(256 * 256 * 2);
  unsigned short* qhg  = (unsigned short*)carve((size_t)B_ * N_ * CQK * 2);
  unsigned short* qlg  = (unsigned short*)carve((size_t)B_ * N_ * CQK * 2);
  unsigned short* khg  = (unsigned short*)carve((size_t)B_ * N_ * CQK * 2);
  unsigned short* klg  = (unsigned short*)carve((size_t)B_ * N_ * CQK * 2);
  unsigned short* vg   = (unsigned short*)carve((size_t)B_ * C_ * N_ * 2);
  unsigned short* Opart = (unsigned short*)carve((size_t)512 * 16384 * 2);  // f16
  float* mlpart = (float*)carve((size_t)512 * 128 * 4);

  k_prep<<<1344, 256, 0, stream>>>(x, xthi, xtlo, Wq, Wk, Wv,
                                   wqh, wql, wkh, wkl, wvh, wvl);
  k_proj<<<dim3(64, 5, B_), 256, 0, stream>>>(wqh, wql, wkh, wkl, wvh, wvl,
                                              xthi, xtlo, bq, bk, bv,
                                              qhg, qlg, khg, klg, vg);
  k_flash<<<512, 512, 0, stream>>>(qhg, qlg, khg, klg, vg, Opart, mlpart);
  k_combine<<<256, 256, 0, stream>>>(Opart, mlpart, x, gamma, out);
}